// Round 1
// baseline (1507.658 us; speedup 1.0000x reference)
//
#include <hip/hip_runtime.h>
#include <math.h>

#define HID 128
#define NRAD 6
#define TABN 2048
#define CUTOFF_INV 0.2f

// T1[z][h] = sum_k emb[z][k] * W_lin[k][h]         (s=0)
// T2[z][h] = sum_k emb[z][k] * W_lin[128+k][h]     (s=1)
__global__ void build_T(const float* __restrict__ emb, const float* __restrict__ W_lin,
                        float* __restrict__ T1, float* __restrict__ T2) {
    int zz = blockIdx.x;
    int s  = blockIdx.y;
    int h  = threadIdx.x;
    __shared__ float er[HID];
    er[h] = emb[zz * HID + h];
    __syncthreads();
    const float* W = W_lin + (size_t)s * HID * HID;
    float acc = 0.f;
#pragma unroll 8
    for (int k = 0; k < HID; ++k) acc += er[k] * W[k * HID + h];
    float* T = (s == 0) ? T1 : T2;
    T[zz * HID + h] = acc;
}

// ftab[t][h] = (silu(rbf(x_t) @ W_rbf + b_rbf)) @ W3,  x_t = t/TABN, rows TABN..TABN+1 = x>=1 (rbf=0)
__global__ void build_ftab(const float* __restrict__ freq, const float* __restrict__ W_rbf,
                           const float* __restrict__ b_rbf, const float* __restrict__ W_lin,
                           float* __restrict__ ftab) {
    int t = blockIdx.x;   // 0..TABN+1
    int h = threadIdx.x;
    __shared__ float hr[HID];

    float fr[NRAD];
#pragma unroll
    for (int k = 0; k < NRAD; ++k) fr[k] = freq[k];

    float rbf[NRAD];
    if (t == 0) {
        // lim x->0 of envelope(x)*sin(f x) = f
#pragma unroll
        for (int k = 0; k < NRAD; ++k) rbf[k] = fr[k];
    } else if (t >= TABN) {
        // x >= 1: envelope gate -> 0
#pragma unroll
        for (int k = 0; k < NRAD; ++k) rbf[k] = 0.f;
    } else {
        float x  = (float)t / (float)TABN;
        float x2 = x * x;
        float x5 = x2 * x2 * x;
        float env = 1.f / x + x5 * (-28.f + x * (48.f + x * (-21.f)));
#pragma unroll
        for (int k = 0; k < NRAD; ++k) rbf[k] = env * sinf(fr[k] * x);
    }

    float pre = b_rbf[h];
#pragma unroll
    for (int k = 0; k < NRAD; ++k) pre += rbf[k] * W_rbf[k * HID + h];
    hr[h] = pre / (1.f + __expf(-pre));   // silu
    __syncthreads();

    const float* W3 = W_lin + (size_t)2 * HID * HID;
    float acc = 0.f;
#pragma unroll 8
    for (int k = 0; k < HID; ++k) acc += hr[k] * W3[k * HID + h];
    ftab[(size_t)t * HID + h] = acc;
}

#define EPB 8   // edges per block (256 threads, 32 threads/edge)

__global__ void edge_kernel(const int* __restrict__ ei, const float* __restrict__ pos,
                            const int* __restrict__ z,
                            const float* __restrict__ T1, const float* __restrict__ T2,
                            const float* __restrict__ ftab, const float* __restrict__ b_lin,
                            float* __restrict__ out, float* __restrict__ cnt, int E) {
    __shared__ int   s_t[EPB];
    __shared__ float s_w[EPB];
    __shared__ int   s_zi[EPB], s_zj[EPB], s_j[EPB];

    int tid = threadIdx.x;
    if (tid < EPB) {
        int e = blockIdx.x * EPB + tid;
        if (e < E) {
            int i = ei[e];
            int j = ei[E + e];
            float dx = pos[3 * i]     - pos[3 * j];
            float dy = pos[3 * i + 1] - pos[3 * j + 1];
            float dz = pos[3 * i + 2] - pos[3 * j + 2];
            float d  = sqrtf(dx * dx + dy * dy + dz * dz);
            float x  = d * CUTOFF_INV;
            float u  = fminf(x, 1.0f) * (float)TABN;
            int   ti = (int)u;
            if (ti > TABN) ti = TABN;
            s_t[tid]  = ti;
            s_w[tid]  = u - (float)ti;
            s_zi[tid] = z[i];
            s_zj[tid] = z[j];
            s_j[tid]  = j;
            atomicAdd(&cnt[j], 1.0f);
        }
    }
    __syncthreads();

    int le = tid >> 5;
    int e  = blockIdx.x * EPB + le;
    if (e >= E) return;
    int h4 = (tid & 31) * 4;

    int   ti = s_t[le];
    float w  = s_w[le];
    const float4 a  = *(const float4*)(ftab + (size_t)ti * HID + h4);
    const float4 b  = *(const float4*)(ftab + (size_t)(ti + 1) * HID + h4);
    const float4 t1 = *(const float4*)(T1 + (size_t)s_zi[le] * HID + h4);
    const float4 t2 = *(const float4*)(T2 + (size_t)s_zj[le] * HID + h4);
    const float4 bl = *(const float4*)(b_lin + h4);

    float p0 = t1.x + t2.x + a.x + w * (b.x - a.x) + bl.x;
    float p1 = t1.y + t2.y + a.y + w * (b.y - a.y) + bl.y;
    float p2 = t1.z + t2.z + a.z + w * (b.z - a.z) + bl.z;
    float p3 = t1.w + t2.w + a.w + w * (b.w - a.w) + bl.w;

    float v0 = p0 / (1.f + __expf(-p0));
    float v1 = p1 / (1.f + __expf(-p1));
    float v2 = p2 / (1.f + __expf(-p2));
    float v3 = p3 / (1.f + __expf(-p3));

    float* dst = out + (size_t)s_j[le] * HID + h4;
    atomicAdd(dst + 0, v0);
    atomicAdd(dst + 1, v1);
    atomicAdd(dst + 2, v2);
    atomicAdd(dst + 3, v3);
}

__global__ void div_kernel(float* __restrict__ out, const float* __restrict__ cnt, int N) {
    int idx = blockIdx.x * blockDim.x + threadIdx.x;   // one float4 per thread
    if (idx >= N * (HID / 4)) return;
    int n = idx >> 5;                                  // (idx*4)/128
    float s = 1.0f / fmaxf(cnt[n], 1.0f);
    float4 v = *(float4*)(out + (size_t)idx * 4);
    v.x *= s; v.y *= s; v.z *= s; v.w *= s;
    *(float4*)(out + (size_t)idx * 4) = v;
}

extern "C" void kernel_launch(void* const* d_in, const int* in_sizes, int n_in,
                              void* d_out, int out_size, void* d_ws, size_t ws_size,
                              hipStream_t stream) {
    const int*   z     = (const int*)d_in[0];
    const float* pos   = (const float*)d_in[1];
    const int*   ei    = (const int*)d_in[2];
    const float* freq  = (const float*)d_in[3];
    const float* emb   = (const float*)d_in[4];
    const float* W_rbf = (const float*)d_in[5];
    const float* b_rbf = (const float*)d_in[6];
    const float* W_lin = (const float*)d_in[7];
    const float* b_lin = (const float*)d_in[8];

    int N    = in_sizes[0];
    int E    = in_sizes[2] / 2;
    int MAXZ = in_sizes[4] / HID;
    float* out = (float*)d_out;

    char* ws = (char*)d_ws;
    float* cnt = (float*)ws;
    size_t off = (((size_t)N * 4) + 255) & ~(size_t)255;
    float* T1 = (float*)(ws + off); off += (size_t)MAXZ * HID * 4;
    off = (off + 255) & ~(size_t)255;
    float* T2 = (float*)(ws + off); off += (size_t)MAXZ * HID * 4;
    off = (off + 255) & ~(size_t)255;
    float* ftab = (float*)(ws + off);

    hipMemsetAsync(d_out, 0, (size_t)out_size * sizeof(float), stream);
    hipMemsetAsync(cnt, 0, (size_t)N * sizeof(float), stream);

    build_T<<<dim3(MAXZ, 2), HID, 0, stream>>>(emb, W_lin, T1, T2);
    build_ftab<<<TABN + 2, HID, 0, stream>>>(freq, W_rbf, b_rbf, W_lin, ftab);
    edge_kernel<<<(E + EPB - 1) / EPB, 256, 0, stream>>>(ei, pos, z, T1, T2, ftab, b_lin,
                                                         out, cnt, E);
    div_kernel<<<((size_t)N * (HID / 4) + 255) / 256, 256, 0, stream>>>(out, cnt, N);
}

// Round 2
// 271.180 us; speedup vs baseline: 5.5596x; 5.5596x over previous
//
#include <hip/hip_runtime.h>
#include <math.h>

#define HID 128
#define NRAD 6
#define TABN 2048
#define CUTOFF_INV 0.2f
#define SCAN_B 1024

// ---------------- table builders (tiny, run once per launch) ----------------

// T1[z][h] = sum_k emb[z][k] * W_lin[k][h]         (s=0)
// T2[z][h] = sum_k emb[z][k] * W_lin[128+k][h]     (s=1)
__global__ void build_T(const float* __restrict__ emb, const float* __restrict__ W_lin,
                        float* __restrict__ T1, float* __restrict__ T2) {
    int zz = blockIdx.x;
    int s  = blockIdx.y;
    int h  = threadIdx.x;
    __shared__ float er[HID];
    er[h] = emb[zz * HID + h];
    __syncthreads();
    const float* W = W_lin + (size_t)s * HID * HID;
    float acc = 0.f;
#pragma unroll 8
    for (int k = 0; k < HID; ++k) acc += er[k] * W[k * HID + h];
    float* T = (s == 0) ? T1 : T2;
    T[zz * HID + h] = acc;
}

// ftab[t][h] = (silu(rbf(x_t) @ W_rbf + b_rbf)) @ W3, x_t = t/TABN; rows TABN, TABN+1 = 0 (x>=1)
__global__ void build_ftab(const float* __restrict__ freq, const float* __restrict__ W_rbf,
                           const float* __restrict__ b_rbf, const float* __restrict__ W_lin,
                           float* __restrict__ ftab) {
    int t = blockIdx.x;   // 0..TABN+1
    int h = threadIdx.x;
    __shared__ float hr[HID];

    float fr[NRAD];
#pragma unroll
    for (int k = 0; k < NRAD; ++k) fr[k] = freq[k];

    float rbf[NRAD];
    if (t == 0) {
#pragma unroll
        for (int k = 0; k < NRAD; ++k) rbf[k] = fr[k];   // lim x->0 env*sin(fx) = f
    } else if (t >= TABN) {
#pragma unroll
        for (int k = 0; k < NRAD; ++k) rbf[k] = 0.f;     // envelope gate
    } else {
        float x  = (float)t / (float)TABN;
        float x2 = x * x;
        float x5 = x2 * x2 * x;
        float env = 1.f / x + x5 * (-28.f + x * (48.f + x * (-21.f)));
#pragma unroll
        for (int k = 0; k < NRAD; ++k) rbf[k] = env * sinf(fr[k] * x);
    }

    float pre = b_rbf[h];
#pragma unroll
    for (int k = 0; k < NRAD; ++k) pre += rbf[k] * W_rbf[k * HID + h];
    hr[h] = pre / (1.f + __expf(-pre));   // silu
    __syncthreads();

    const float* W3 = W_lin + (size_t)2 * HID * HID;
    float acc = 0.f;
#pragma unroll 8
    for (int k = 0; k < HID; ++k) acc += hr[k] * W3[k * HID + h];
    ftab[(size_t)t * HID + h] = acc;
}

// ---------------- CSR build: count -> scan -> scatter ----------------

__global__ void count_k(const int* __restrict__ ej, int* __restrict__ cnt, int E) {
    int e = blockIdx.x * 256 + threadIdx.x;
    if (e < E) atomicAdd(&cnt[ej[e]], 1);
}

__global__ void scan1(const int* __restrict__ cnt, int* __restrict__ offs,
                      int* __restrict__ bsum, int N) {
    __shared__ int sh[SCAN_B];
    int n = blockIdx.x * SCAN_B + threadIdx.x;
    int v = (n < N) ? cnt[n] : 0;
    sh[threadIdx.x] = v;
    __syncthreads();
    for (int off = 1; off < SCAN_B; off <<= 1) {
        int t = (threadIdx.x >= off) ? sh[threadIdx.x - off] : 0;
        __syncthreads();
        sh[threadIdx.x] += t;
        __syncthreads();
    }
    if (n < N) offs[n] = sh[threadIdx.x] - v;           // exclusive within block
    if (threadIdx.x == SCAN_B - 1) bsum[blockIdx.x] = sh[threadIdx.x];
}

__global__ void scan2(int* __restrict__ bsum, int NB) {
    if (threadIdx.x == 0) {
        int acc = 0;
        for (int b = 0; b < NB; ++b) { int t = bsum[b]; bsum[b] = acc; acc += t; }
    }
}

__global__ void scan3(int* __restrict__ offs, int* __restrict__ cursor,
                      const int* __restrict__ bsum, int N, int E) {
    int n = blockIdx.x * SCAN_B + threadIdx.x;
    if (n < N) {
        int o = offs[n] + bsum[blockIdx.x];
        offs[n]   = o;
        cursor[n] = o;
    }
    if (n == 0) offs[N] = E;
}

// per-edge payload: {ti, w(bits), z[i], z[j]} written to CSR slot of node j
__global__ void scatter_k(const int* __restrict__ ei, const float* __restrict__ pos,
                          const int* __restrict__ z, int* __restrict__ cursor,
                          int4* __restrict__ payload, int E) {
    int e = blockIdx.x * 256 + threadIdx.x;
    if (e >= E) return;
    int i = ei[e];
    int j = ei[E + e];
    float dx = pos[3 * i]     - pos[3 * j];
    float dy = pos[3 * i + 1] - pos[3 * j + 1];
    float dz = pos[3 * i + 2] - pos[3 * j + 2];
    float d  = sqrtf(dx * dx + dy * dy + dz * dz);
    float u  = fminf(d * CUTOFF_INV, 1.0f) * (float)TABN;
    int   ti = (int)u;
    if (ti > TABN) ti = TABN;
    int4 pl;
    pl.x = ti;
    pl.y = __float_as_int(u - (float)ti);
    pl.z = z[i];
    pl.w = z[j];
    int p = atomicAdd(&cursor[j], 1);
    payload[p] = pl;
}

// ---------------- node-centric gather: 32 lanes per node ----------------

__global__ void gather_k(const int* __restrict__ offs, const int4* __restrict__ payload,
                         const float* __restrict__ T1, const float* __restrict__ T2,
                         const float* __restrict__ ftab, const float* __restrict__ b_lin,
                         float* __restrict__ out, int N) {
    int tid  = threadIdx.x;
    int lane = tid & 31;
    int n    = blockIdx.x * 8 + (tid >> 5);
    if (n >= N) return;
    int h4  = lane * 4;
    int beg = offs[n];
    int end = offs[n + 1];
    const float4 bl = *(const float4*)(b_lin + h4);

    float a0 = 0.f, a1 = 0.f, a2 = 0.f, a3 = 0.f;
    for (int e = beg; e < end; ++e) {
        int4  pl = payload[e];                       // broadcast load (same addr, 32 lanes)
        float w  = __int_as_float(pl.y);
        const float4 fa = *(const float4*)(ftab + (size_t)pl.x * HID + h4);
        const float4 fb = *(const float4*)(ftab + (size_t)(pl.x + 1) * HID + h4);
        const float4 t1 = *(const float4*)(T1 + (size_t)pl.z * HID + h4);
        const float4 t2 = *(const float4*)(T2 + (size_t)pl.w * HID + h4);

        float p0 = t1.x + t2.x + fa.x + w * (fb.x - fa.x) + bl.x;
        float p1 = t1.y + t2.y + fa.y + w * (fb.y - fa.y) + bl.y;
        float p2 = t1.z + t2.z + fa.z + w * (fb.z - fa.z) + bl.z;
        float p3 = t1.w + t2.w + fa.w + w * (fb.w - fa.w) + bl.w;

        a0 += p0 / (1.f + __expf(-p0));
        a1 += p1 / (1.f + __expf(-p1));
        a2 += p2 / (1.f + __expf(-p2));
        a3 += p3 / (1.f + __expf(-p3));
    }
    float s = (end > beg) ? 1.0f / (float)(end - beg) : 0.0f;
    float4 v;
    v.x = a0 * s; v.y = a1 * s; v.z = a2 * s; v.w = a3 * s;
    *(float4*)(out + (size_t)n * HID + h4) = v;
}

// ---------------- launch ----------------

extern "C" void kernel_launch(void* const* d_in, const int* in_sizes, int n_in,
                              void* d_out, int out_size, void* d_ws, size_t ws_size,
                              hipStream_t stream) {
    const int*   z     = (const int*)d_in[0];
    const float* pos   = (const float*)d_in[1];
    const int*   ei    = (const int*)d_in[2];
    const float* freq  = (const float*)d_in[3];
    const float* emb   = (const float*)d_in[4];
    const float* W_rbf = (const float*)d_in[5];
    const float* b_rbf = (const float*)d_in[6];
    const float* W_lin = (const float*)d_in[7];
    const float* b_lin = (const float*)d_in[8];

    int N    = in_sizes[0];
    int E    = in_sizes[2] / 2;
    int MAXZ = in_sizes[4] / HID;
    float* out = (float*)d_out;

    int NB = (N + SCAN_B - 1) / SCAN_B;

    char* ws = (char*)d_ws;
    size_t off = 0;
    auto alloc = [&](size_t bytes) { char* p = ws + off; off = (off + bytes + 255) & ~(size_t)255; return p; };
    int*   cnt    = (int*)alloc((size_t)N * 4);
    int*   offs   = (int*)alloc((size_t)(N + 1) * 4);
    int*   cursor = (int*)alloc((size_t)N * 4);
    int*   bsum   = (int*)alloc((size_t)NB * 4);
    float* T1     = (float*)alloc((size_t)MAXZ * HID * 4);
    float* T2     = (float*)alloc((size_t)MAXZ * HID * 4);
    float* ftab   = (float*)alloc((size_t)(TABN + 2) * HID * 4);
    int4*  payload = (int4*)alloc((size_t)E * 16);

    hipMemsetAsync(cnt, 0, (size_t)N * 4, stream);

    build_T<<<dim3(MAXZ, 2), HID, 0, stream>>>(emb, W_lin, T1, T2);
    build_ftab<<<TABN + 2, HID, 0, stream>>>(freq, W_rbf, b_rbf, W_lin, ftab);

    count_k<<<(E + 255) / 256, 256, 0, stream>>>(ei + E, cnt, E);
    scan1<<<NB, SCAN_B, 0, stream>>>(cnt, offs, bsum, N);
    scan2<<<1, 64, 0, stream>>>(bsum, NB);
    scan3<<<NB, SCAN_B, 0, stream>>>(offs, cursor, bsum, N, E);
    scatter_k<<<(E + 255) / 256, 256, 0, stream>>>(ei, pos, z, cursor, payload, E);
    gather_k<<<(N + 7) / 8, 256, 0, stream>>>(offs, payload, T1, T2, ftab, b_lin, out, N);
}

// Round 3
// 241.741 us; speedup vs baseline: 6.2367x; 1.1218x over previous
//
#include <hip/hip_runtime.h>
#include <math.h>

#define HID 128
#define NRAD 6
#define TABN 2048
#define CUTOFF_INV 0.2f

// ---------------- K1: build T1/T2 (z-embedding @ W1/W2) + ftab, 128 threads ----------------
// T1[z][h] = emb[z] @ W_lin[0:128]  ;  T2[z][h] = emb[z] @ W_lin[128:256]
// ftab[t][h] = silu(rbf(t/TABN) @ W_rbf + b_rbf) @ W_lin[256:384]; rows TABN,TABN+1 = 0
__global__ void build1(const float* __restrict__ emb, const float* __restrict__ W_lin,
                       const float* __restrict__ freq, const float* __restrict__ W_rbf,
                       const float* __restrict__ b_rbf,
                       float* __restrict__ T1, float* __restrict__ T2,
                       float* __restrict__ ftab, int MAXZ) {
    __shared__ float sh[HID];
    int h   = threadIdx.x;
    int bid = blockIdx.x;
    if (bid < 2 * MAXZ) {
        int zz = bid >> 1, s = bid & 1;
        sh[h] = emb[zz * HID + h];
        __syncthreads();
        const float* W = W_lin + (size_t)s * HID * HID;
        float acc = 0.f;
#pragma unroll 8
        for (int k = 0; k < HID; ++k) acc += sh[k] * W[k * HID + h];
        ((s == 0) ? T1 : T2)[zz * HID + h] = acc;
    } else {
        int t = bid - 2 * MAXZ;   // 0..TABN+1
        float fr[NRAD];
#pragma unroll
        for (int k = 0; k < NRAD; ++k) fr[k] = freq[k];
        float rbf[NRAD];
        if (t == 0) {
#pragma unroll
            for (int k = 0; k < NRAD; ++k) rbf[k] = fr[k];   // lim x->0 env*sin(fx)=f
        } else if (t >= TABN) {
#pragma unroll
            for (int k = 0; k < NRAD; ++k) rbf[k] = 0.f;     // envelope gate x>=1
        } else {
            float x  = (float)t / (float)TABN;
            float x2 = x * x;
            float x5 = x2 * x2 * x;
            float env = 1.f / x + x5 * (-28.f + x * (48.f + x * (-21.f)));
#pragma unroll
            for (int k = 0; k < NRAD; ++k) rbf[k] = env * sinf(fr[k] * x);
        }
        float pre = b_rbf[h];
#pragma unroll
        for (int k = 0; k < NRAD; ++k) pre += rbf[k] * W_rbf[k * HID + h];
        sh[h] = pre / (1.f + __expf(-pre));   // silu (once per table row, precision-first)
        __syncthreads();
        const float* W3 = W_lin + (size_t)2 * HID * HID;
        float acc = 0.f;
#pragma unroll 8
        for (int k = 0; k < HID; ++k) acc += sh[k] * W3[k * HID + h];
        ftab[(size_t)t * HID + h] = acc;
    }
}

// ---------------- K2: fused T12 build + degree count, 256 threads ----------------
// T12[zi*MAXZ+zj][h] = T1[zi][h] + T2[zj][h] + b_lin[h]
__global__ void build2(const float* __restrict__ T1, const float* __restrict__ T2,
                       const float* __restrict__ b_lin, float* __restrict__ T12,
                       const int* __restrict__ ej, int* __restrict__ cnt,
                       int MAXZ, int E, int nT12) {
    int bid = blockIdx.x;
    if (bid < nT12) {
        int idx = bid * 256 + threadIdx.x;
        int tot = MAXZ * MAXZ * HID;
        if (idx < tot) {
            int r  = idx >> 7;
            int h  = idx & (HID - 1);
            int zi = r / MAXZ;
            int zj = r - zi * MAXZ;
            T12[idx] = T1[zi * HID + h] + T2[zj * HID + h] + b_lin[h];
        }
    } else {
        int e = (bid - nT12) * 256 + threadIdx.x;
        if (e < E) atomicAdd(&cnt[ej[e]], 1);
    }
}

// ---------------- scan: 1024 elems/block, 256 threads, shfl-based ----------------
__global__ void scan1(const int* __restrict__ cnt, int* __restrict__ offs,
                      int* __restrict__ bsum) {
    int t = threadIdx.x;
    size_t base = (size_t)blockIdx.x * 1024 + t * 4;
    int4 v = *(const int4*)(cnt + base);
    int s0 = v.x, s1 = s0 + v.y, s2 = s1 + v.z, s3 = s2 + v.w;  // thread-inclusive
    int lane = t & 63, wv = t >> 6;
    int incl = s3;
#pragma unroll
    for (int off = 1; off < 64; off <<= 1) {
        int u = __shfl_up(incl, off, 64);
        if (lane >= off) incl += u;
    }
    __shared__ int ws[4];
    if (lane == 63) ws[wv] = incl;
    __syncthreads();
    int wbase = 0;
    for (int w = 0; w < wv; ++w) wbase += ws[w];
    int ex = wbase + incl - s3;          // exclusive prefix before this thread's 4
    int4 o;
    o.x = ex; o.y = ex + s0; o.z = ex + s1; o.w = ex + s2;
    *(int4*)(offs + base) = o;
    if (t == 255) bsum[blockIdx.x] = wbase + incl;
}

__global__ void scan2(int* __restrict__ bsum, int NB) {   // 1 block, 256 threads, NB<=256
    int t = threadIdx.x;
    int v = (t < NB) ? bsum[t] : 0;
    int lane = t & 63, wv = t >> 6;
    int incl = v;
#pragma unroll
    for (int off = 1; off < 64; off <<= 1) {
        int u = __shfl_up(incl, off, 64);
        if (lane >= off) incl += u;
    }
    __shared__ int ws[4];
    if (lane == 63) ws[wv] = incl;
    __syncthreads();
    int wbase = 0;
    for (int w = 0; w < wv; ++w) wbase += ws[w];
    if (t < NB) bsum[t] = wbase + incl - v;   // exclusive
}

__global__ void scan3(int* __restrict__ offs, int* __restrict__ cursor,
                      const int* __restrict__ bsum) {
    size_t base = (size_t)blockIdx.x * 1024 + threadIdx.x * 4;
    int add = bsum[blockIdx.x];
    int4 o = *(int4*)(offs + base);
    o.x += add; o.y += add; o.z += add; o.w += add;
    *(int4*)(offs + base)   = o;
    *(int4*)(cursor + base) = o;
}

// ---------------- scatter: packed 8-byte payload into CSR slot of node j ----------------
// pl.x = ti (12b) | (zi*MAXZ+zj) << 12 ; pl.y = bits of lerp weight w
__global__ void scatter_k(const int* __restrict__ ei, const float* __restrict__ pos,
                          const int* __restrict__ z, int* __restrict__ cursor,
                          int2* __restrict__ payload, int E, int MAXZ) {
    int e = blockIdx.x * 256 + threadIdx.x;
    if (e >= E) return;
    int i = ei[e];
    int j = ei[E + e];
    float dx = pos[3 * i]     - pos[3 * j];
    float dy = pos[3 * i + 1] - pos[3 * j + 1];
    float dz = pos[3 * i + 2] - pos[3 * j + 2];
    float d  = sqrtf(dx * dx + dy * dy + dz * dz);
    float u  = fminf(d * CUTOFF_INV, 1.0f) * (float)TABN;
    int   ti = (int)u;
    if (ti > TABN) ti = TABN;
    int zij = z[i] * MAXZ + z[j];
    int2 pl;
    pl.x = ti | (zij << 12);
    pl.y = __float_as_int(u - (float)ti);
    payload[atomicAdd(&cursor[j], 1)] = pl;
}

// ---------------- gather: 32 lanes per node, silu via v_rcp ----------------
__launch_bounds__(256)
__global__ void gather_k(const int* __restrict__ offs, const int2* __restrict__ payload,
                         const float* __restrict__ T12, const float* __restrict__ ftab,
                         float* __restrict__ out, int N) {
    int tid  = threadIdx.x;
    int lane = tid & 31;
    int n    = blockIdx.x * 8 + (tid >> 5);
    if (n >= N) return;
    int h4  = lane * 4;
    int beg = offs[n];
    int end = offs[n + 1];
    const float* ft = ftab + h4;
    const float* tt = T12 + h4;

    float a0 = 0.f, a1 = 0.f, a2 = 0.f, a3 = 0.f;
    auto body = [&](int e) {
        int2  pl  = payload[e];                 // broadcast across the 32 lanes
        int   ti  = pl.x & 0xFFF;
        int   zij = ((unsigned)pl.x) >> 12;
        float w   = __int_as_float(pl.y);
        float4 fa = *(const float4*)(ft + (size_t)ti * HID);
        float4 fb = *(const float4*)(ft + (size_t)(ti + 1) * HID);
        float4 t  = *(const float4*)(tt + (size_t)zij * HID);
        float p0 = t.x + fa.x + w * (fb.x - fa.x);
        float p1 = t.y + fa.y + w * (fb.y - fa.y);
        float p2 = t.z + fa.z + w * (fb.z - fa.z);
        float p3 = t.w + fa.w + w * (fb.w - fa.w);
        a0 = fmaf(p0, __builtin_amdgcn_rcpf(1.f + __expf(-p0)), a0);
        a1 = fmaf(p1, __builtin_amdgcn_rcpf(1.f + __expf(-p1)), a1);
        a2 = fmaf(p2, __builtin_amdgcn_rcpf(1.f + __expf(-p2)), a2);
        a3 = fmaf(p3, __builtin_amdgcn_rcpf(1.f + __expf(-p3)), a3);
    };
    int e = beg;
    for (; e + 1 < end; e += 2) { body(e); body(e + 1); }
    if (e < end) body(e);

    float s = (end > beg) ? 1.0f / (float)(end - beg) : 0.0f;
    float4 v;
    v.x = a0 * s; v.y = a1 * s; v.z = a2 * s; v.w = a3 * s;
    *(float4*)(out + (size_t)n * HID + h4) = v;
}

// ---------------- launch ----------------
extern "C" void kernel_launch(void* const* d_in, const int* in_sizes, int n_in,
                              void* d_out, int out_size, void* d_ws, size_t ws_size,
                              hipStream_t stream) {
    const int*   z     = (const int*)d_in[0];
    const float* pos   = (const float*)d_in[1];
    const int*   ei    = (const int*)d_in[2];
    const float* freq  = (const float*)d_in[3];
    const float* emb   = (const float*)d_in[4];
    const float* W_rbf = (const float*)d_in[5];
    const float* b_rbf = (const float*)d_in[6];
    const float* W_lin = (const float*)d_in[7];
    const float* b_lin = (const float*)d_in[8];

    int N    = in_sizes[0];
    int E    = in_sizes[2] / 2;
    int MAXZ = in_sizes[4] / HID;
    float* out = (float*)d_out;

    int N_pad = ((N + 1023) / 1024) * 1024;
    int NB    = N_pad / 1024;

    char* ws = (char*)d_ws;
    size_t off = 0;
    auto alloc = [&](size_t bytes) { char* p = ws + off; off = (off + bytes + 255) & ~(size_t)255; return p; };
    int*   cnt    = (int*)alloc((size_t)N_pad * 4);
    int*   offs   = (int*)alloc((size_t)(N_pad + 4) * 4);
    int*   cursor = (int*)alloc((size_t)(N_pad + 4) * 4);
    int*   bsum   = (int*)alloc((size_t)NB * 4);
    float* T1     = (float*)alloc((size_t)MAXZ * HID * 4);
    float* T2     = (float*)alloc((size_t)MAXZ * HID * 4);
    float* T12    = (float*)alloc((size_t)MAXZ * MAXZ * HID * 4);
    float* ftab   = (float*)alloc((size_t)(TABN + 2) * HID * 4);
    int2*  payload = (int2*)alloc((size_t)E * 8);

    hipMemsetAsync(cnt, 0, (size_t)N_pad * 4, stream);

    build1<<<2 * MAXZ + TABN + 2, HID, 0, stream>>>(emb, W_lin, freq, W_rbf, b_rbf,
                                                    T1, T2, ftab, MAXZ);
    int nT12 = (MAXZ * MAXZ * HID + 255) / 256;
    build2<<<nT12 + (E + 255) / 256, 256, 0, stream>>>(T1, T2, b_lin, T12,
                                                       ei + E, cnt, MAXZ, E, nT12);
    scan1<<<NB, 256, 0, stream>>>(cnt, offs, bsum);
    scan2<<<1, 256, 0, stream>>>(bsum, NB);
    scan3<<<NB, 256, 0, stream>>>(offs, cursor, bsum);
    scatter_k<<<(E + 255) / 256, 256, 0, stream>>>(ei, pos, z, cursor, payload, E, MAXZ);
    gather_k<<<(N + 7) / 8, 256, 0, stream>>>(offs, payload, T12, ftab, out, N);
}

// Round 4
// 229.099 us; speedup vs baseline: 6.5808x; 1.0552x over previous
//
#include <hip/hip_runtime.h>
#include <hip/hip_bf16.h>
#include <math.h>

#define HID 128
#define NRAD 6
#define TABN 4096          // nearest-neighbor table, rows 0..TABN (row TABN = 0, x>=1 gate)
#define CUTOFF_INV 0.2f
#define MZ 95              // MAX_Z (LDS statically sized for this)

typedef unsigned int uint32;

// ---------------- K1: T1(+b_lin)/T2 as bf16, ftab fp32 nearest, degree count ----------------
__global__ void build1(const float* __restrict__ emb, const float* __restrict__ W_lin,
                       const float* __restrict__ freq, const float* __restrict__ W_rbf,
                       const float* __restrict__ b_rbf, const float* __restrict__ b_lin,
                       __hip_bfloat16* __restrict__ Tb, float* __restrict__ ftab,
                       const int* __restrict__ ej, int* __restrict__ cnt,
                       int MAXZ, int E) {
    __shared__ float sh[HID];
    int h   = threadIdx.x;
    int bid = blockIdx.x;
    int nT  = 2 * MAXZ;
    int nF  = TABN + 1;
    if (bid < nT) {
        int zz = bid >> 1, s = bid & 1;
        sh[h] = emb[zz * HID + h];
        __syncthreads();
        const float* W = W_lin + (size_t)s * HID * HID;
        float acc = (s == 0) ? b_lin[h] : 0.f;   // fold bias into T1
#pragma unroll 8
        for (int k = 0; k < HID; ++k) acc += sh[k] * W[k * HID + h];
        Tb[(size_t)(s * MAXZ + zz) * HID + h] = __float2bfloat16(acc);
    } else if (bid < nT + nF) {
        int t = bid - nT;   // 0..TABN
        float fr[NRAD];
#pragma unroll
        for (int k = 0; k < NRAD; ++k) fr[k] = freq[k];
        float rbf[NRAD];
        if (t == 0) {
#pragma unroll
            for (int k = 0; k < NRAD; ++k) rbf[k] = fr[k];   // lim x->0 env*sin(fx)=f
        } else if (t >= TABN) {
#pragma unroll
            for (int k = 0; k < NRAD; ++k) rbf[k] = 0.f;     // envelope gate x>=1
        } else {
            float x  = (float)t / (float)TABN;
            float x2 = x * x;
            float x5 = x2 * x2 * x;
            float env = 1.f / x + x5 * (-28.f + x * (48.f + x * (-21.f)));
#pragma unroll
            for (int k = 0; k < NRAD; ++k) rbf[k] = env * sinf(fr[k] * x);
        }
        float pre = b_rbf[h];
#pragma unroll
        for (int k = 0; k < NRAD; ++k) pre += rbf[k] * W_rbf[k * HID + h];
        sh[h] = pre / (1.f + __expf(-pre));   // precise silu (once per table row)
        __syncthreads();
        const float* W3 = W_lin + (size_t)2 * HID * HID;
        float acc = 0.f;
#pragma unroll 8
        for (int k = 0; k < HID; ++k) acc += sh[k] * W3[k * HID + h];
        ftab[(size_t)t * HID + h] = acc;
    } else {
        int e = (bid - nT - nF) * HID + h;
        if (e < E) atomicAdd(&cnt[ej[e]], 1);
    }
}

// ---------------- scan: 1024 elems/block, 256 threads, shfl-based ----------------
__global__ void scan1(const int* __restrict__ cnt, int* __restrict__ offs,
                      int* __restrict__ bsum) {
    int t = threadIdx.x;
    size_t base = (size_t)blockIdx.x * 1024 + t * 4;
    int4 v = *(const int4*)(cnt + base);
    int s0 = v.x, s1 = s0 + v.y, s2 = s1 + v.z, s3 = s2 + v.w;
    int lane = t & 63, wv = t >> 6;
    int incl = s3;
#pragma unroll
    for (int off = 1; off < 64; off <<= 1) {
        int u = __shfl_up(incl, off, 64);
        if (lane >= off) incl += u;
    }
    __shared__ int ws[4];
    if (lane == 63) ws[wv] = incl;
    __syncthreads();
    int wbase = 0;
    for (int w = 0; w < wv; ++w) wbase += ws[w];
    int ex = wbase + incl - s3;
    int4 o;
    o.x = ex; o.y = ex + s0; o.z = ex + s1; o.w = ex + s2;
    *(int4*)(offs + base) = o;
    if (t == 255) bsum[blockIdx.x] = wbase + incl;
}

__global__ void scan2(int* __restrict__ bsum, int NB) {   // 1 block, NB<=256
    int t = threadIdx.x;
    int v = (t < NB) ? bsum[t] : 0;
    int lane = t & 63, wv = t >> 6;
    int incl = v;
#pragma unroll
    for (int off = 1; off < 64; off <<= 1) {
        int u = __shfl_up(incl, off, 64);
        if (lane >= off) incl += u;
    }
    __shared__ int ws[4];
    if (lane == 63) ws[wv] = incl;
    __syncthreads();
    int wbase = 0;
    for (int w = 0; w < wv; ++w) wbase += ws[w];
    if (t < NB) bsum[t] = wbase + incl - v;
}

__global__ void scan3(int* __restrict__ offs, int* __restrict__ cursor,
                      const int* __restrict__ bsum) {
    size_t base = (size_t)blockIdx.x * 1024 + threadIdx.x * 4;
    int add = bsum[blockIdx.x];
    int4 o = *(int4*)(offs + base);
    o.x += add; o.y += add; o.z += add; o.w += add;
    *(int4*)(offs + base)   = o;
    *(int4*)(cursor + base) = o;
}

// ---------------- scatter: 4-byte packed payload {ti:13 | zi:7 | zj:7} ----------------
__global__ void scatter_k(const int* __restrict__ ei, const float* __restrict__ pos,
                          const int* __restrict__ z, int* __restrict__ cursor,
                          int* __restrict__ payload, int E) {
    int e = blockIdx.x * 256 + threadIdx.x;
    if (e >= E) return;
    int i = ei[e];
    int j = ei[E + e];
    float dx = pos[3 * i]     - pos[3 * j];
    float dy = pos[3 * i + 1] - pos[3 * j + 1];
    float dz = pos[3 * i + 2] - pos[3 * j + 2];
    float d  = sqrtf(dx * dx + dy * dy + dz * dz);
    float u  = fminf(d * CUTOFF_INV, 1.0f) * (float)TABN;
    int   ti = (int)(u + 0.5f);          // nearest
    if (ti > TABN) ti = TABN;
    int pl = ti | (z[i] << 13) | (z[j] << 20);
    payload[atomicAdd(&cursor[j], 1)] = pl;
}

// ---------------- gather: 32 lanes/node, T1/T2 bf16 in LDS, persistent blocks ----------------
__launch_bounds__(1024, 8)
__global__ void gather_k(const int* __restrict__ offs, const int* __restrict__ payload,
                         const uint32* __restrict__ Tb32, const float* __restrict__ ftab,
                         float* __restrict__ out, int N) {
    __shared__ uint32 sT[2 * MZ * (HID / 2)];    // 12160 uints = 48640 B (bf16 pairs)
    int tid = threadIdx.x;
    for (int k = tid; k < 2 * MZ * (HID / 2); k += 1024) sT[k] = Tb32[k];
    __syncthreads();

    int lane = tid & 31;
    int grp  = tid >> 5;            // 0..31 node-groups per block
    int h4   = lane * 4;
    const float* ft = ftab + h4;
    const uint32* sT2b = sT + MZ * (HID / 2);
    int nCh = (N + 31) >> 5;

    for (int ch = blockIdx.x; ch < nCh; ch += gridDim.x) {
        int n = (ch << 5) + grp;
        if (n >= N) continue;
        int beg = offs[n];
        int end = offs[n + 1];

        float a0 = 0.f, a1 = 0.f, a2 = 0.f, a3 = 0.f;
        auto body = [&](int e) {
            int pl = payload[e];                     // broadcast across 32 lanes
            int ti = pl & 0x1FFF;
            int zi = (pl >> 13) & 0x7F;
            int zj = (pl >> 20) & 0x7F;
            float4 f = *(const float4*)(ft + (size_t)ti * HID);
            uint2  u1 = *(const uint2*)(sT   + zi * (HID / 2) + lane * 2);
            uint2  u2 = *(const uint2*)(sT2b + zj * (HID / 2) + lane * 2);
            float p0 = __uint_as_float(u1.x << 16)         + __uint_as_float(u2.x << 16)         + f.x;
            float p1 = __uint_as_float(u1.x & 0xFFFF0000u) + __uint_as_float(u2.x & 0xFFFF0000u) + f.y;
            float p2 = __uint_as_float(u1.y << 16)         + __uint_as_float(u2.y << 16)         + f.z;
            float p3 = __uint_as_float(u1.y & 0xFFFF0000u) + __uint_as_float(u2.y & 0xFFFF0000u) + f.w;
            a0 = fmaf(p0, __builtin_amdgcn_rcpf(1.f + __expf(-p0)), a0);
            a1 = fmaf(p1, __builtin_amdgcn_rcpf(1.f + __expf(-p1)), a1);
            a2 = fmaf(p2, __builtin_amdgcn_rcpf(1.f + __expf(-p2)), a2);
            a3 = fmaf(p3, __builtin_amdgcn_rcpf(1.f + __expf(-p3)), a3);
        };
        int e = beg;
        for (; e + 1 < end; e += 2) { body(e); body(e + 1); }
        if (e < end) body(e);

        float s = (end > beg) ? 1.0f / (float)(end - beg) : 0.0f;
        float4 v;
        v.x = a0 * s; v.y = a1 * s; v.z = a2 * s; v.w = a3 * s;
        *(float4*)(out + (size_t)n * HID + h4) = v;
    }
}

// ---------------- launch ----------------
extern "C" void kernel_launch(void* const* d_in, const int* in_sizes, int n_in,
                              void* d_out, int out_size, void* d_ws, size_t ws_size,
                              hipStream_t stream) {
    const int*   z     = (const int*)d_in[0];
    const float* pos   = (const float*)d_in[1];
    const int*   ei    = (const int*)d_in[2];
    const float* freq  = (const float*)d_in[3];
    const float* emb   = (const float*)d_in[4];
    const float* W_rbf = (const float*)d_in[5];
    const float* b_rbf = (const float*)d_in[6];
    const float* W_lin = (const float*)d_in[7];
    const float* b_lin = (const float*)d_in[8];

    int N    = in_sizes[0];
    int E    = in_sizes[2] / 2;
    int MAXZ = in_sizes[4] / HID;   // = MZ = 95
    float* out = (float*)d_out;

    int N_pad = ((N + 1024) / 1024) * 1024;   // always strictly > N so offs[N] is written
    int NB    = N_pad / 1024;

    char* ws = (char*)d_ws;
    size_t off = 0;
    auto alloc = [&](size_t bytes) { char* p = ws + off; off = (off + bytes + 255) & ~(size_t)255; return p; };
    int*   cnt    = (int*)alloc((size_t)N_pad * 4);
    int*   offs   = (int*)alloc((size_t)N_pad * 4);
    int*   cursor = (int*)alloc((size_t)N_pad * 4);
    int*   bsum   = (int*)alloc((size_t)NB * 4);
    __hip_bfloat16* Tb = (__hip_bfloat16*)alloc((size_t)2 * MAXZ * HID * 2);
    float* ftab   = (float*)alloc((size_t)(TABN + 1) * HID * 4);
    int*   payload = (int*)alloc((size_t)E * 4);

    hipMemsetAsync(cnt, 0, (size_t)N_pad * 4, stream);

    int nBuild = 2 * MAXZ + (TABN + 1) + (E + HID - 1) / HID;
    build1<<<nBuild, HID, 0, stream>>>(emb, W_lin, freq, W_rbf, b_rbf, b_lin,
                                       Tb, ftab, ei + E, cnt, MAXZ, E);
    scan1<<<NB, 256, 0, stream>>>(cnt, offs, bsum);
    scan2<<<1, 256, 0, stream>>>(bsum, NB);
    scan3<<<NB, 256, 0, stream>>>(offs, cursor, bsum);
    scatter_k<<<(E + 255) / 256, 256, 0, stream>>>(ei, pos, z, cursor, payload, E);
    gather_k<<<512, 1024, 0, stream>>>(offs, payload, (const uint32*)Tb, ftab, out, N);
}